// Round 6
// baseline (682.850 us; speedup 1.0000x reference)
//
#include <hip/hip_runtime.h>
#include <math.h>

// SSIM, separable column-pipeline, 2 columns/thread, BARRIER-FREE.
// img1,img2: [32,3,512,512] fp32 -> scalar mean.
//
// ssim_kernel: 256 threads = 4 INDEPENDENT waves; each wave owns a 128-col
// strip (+5-col halo = 138 staged (a,b) pairs) of a TH=64-row band.
//  - wave-private LDS double buffer (no __syncthreads in the loop; per-wave
//    DS ordering + compiler waitcnts are the only sync).
//  - pipeline per iter r: ds_write row r+1 (from prefetch regs), THEN issue
//    global loads for row r+2 (so the vmcnt wait covers only the old batch),
//    ds_read row r window (6 x ds_read_b128, 16B-aligned), compute.
//  - 11-tap h-conv for 2 cols; v-conv in an 11-slot x 5-qty float2 register
//    ring with compile-time indices; weight-0 tap assigns (no resets).
//  - rcp instead of divide; per-thread sum -> one end-of-kernel block
//    reduction (the only barrier) -> 1 float partial per block (768 total).
// reduce_kernel: single block sums 768 partials in double, writes mean.
//
// Lessons kept: launch_bounds(256,N>1) caps VGPR at 256/N and spills the
// ~180-reg live state (rounds 2/4: WRITE_SIZE 711/623 MB) -> use (256,1).
// Round-5 lesson: per-iter __syncthreads at 2 waves/SIMD = 61% stall.

#define IH 512
#define IW 512
#define NCH 96            // 32*3 depthwise channels
#define TH 64             // output rows per block
#define NE 138            // staged pairs per wave row: 128 + 2*5 halo
#define NEP 140           // padded pair stride (140*8B = 16B-aligned rows)
#define C1f (0.01f * 0.01f)
#define C2f (0.03f * 0.03f)

struct Weights { float w[11]; };

__device__ __forceinline__ float ssim_px(float mu1, float mu2, float m11,
                                         float m22, float m12) {
    const float mu1s = mu1 * mu1;
    const float mu2s = mu2 * mu2;
    const float mu12 = mu1 * mu2;
    const float num = (2.f * mu12 + C1f) * (2.f * (m12 - mu12) + C2f);
    const float den = (mu1s + mu2s + C1f) * ((m11 - mu1s) + (m22 - mu2s) + C2f);
    return num * __builtin_amdgcn_rcpf(den);
}

__global__ __launch_bounds__(256, 1) void ssim_kernel(
    const float* __restrict__ img1, const float* __restrict__ img2,
    float* __restrict__ partial, Weights wt)
{
    __shared__ __align__(16) float2 sAB[4][2][NEP];  // [wave][parity][pair]
    __shared__ float wave_sums[4];

    const int tid = threadIdx.x;
    const int l   = tid & 63;        // lane
    const int wv  = tid >> 6;        // wave id (strip id)
    const int bx  = blockIdx.x;
    const int ty  = bx & 7;          // 8 row bands
    const int ch  = bx >> 3;         // 96 channels

    const int row_out0 = ty * TH;
    const int row0     = row_out0 - 5;   // staged row r -> global row row0+r
    const float* __restrict__ p1 = img1 + (size_t)ch * (IH * IW);
    const float* __restrict__ p2 = img2 + (size_t)ch * (IH * IW);

    // staged entry e (0..137) of this wave's strip <-> global col colbase+e
    const int colbase = (wv << 7) - 5;
    const int c0 = colbase + l;          // entry l
    const int c1 = colbase + l + 64;     // entry l+64
    const int c2 = colbase + l + 128;    // entry l+128 (written by l<10)
    const bool v0 = ((unsigned)c0 < (unsigned)IW);
    const bool v1 = ((unsigned)c1 < (unsigned)IW);
    const bool v2 = ((unsigned)c2 < (unsigned)IW);
    const int cc0 = v0 ? c0 : 0;         // clamped (safe) columns
    const int cc1 = v1 ? c1 : 0;
    const int cc2 = v2 ? c2 : 0;

    // prefetch registers (one staged row in flight)
    float a0, b0, a1, b1, a2, b2;

    auto load_row = [&](int r) {
        const int gr = row0 + r;                     // wave-uniform
        if ((unsigned)gr < (unsigned)IH) {           // uniform branch
            const int ro = gr * IW;
            float t;
            t = p1[ro + cc0]; a0 = v0 ? t : 0.f;
            t = p2[ro + cc0]; b0 = v0 ? t : 0.f;
            t = p1[ro + cc1]; a1 = v1 ? t : 0.f;
            t = p2[ro + cc1]; b1 = v1 ? t : 0.f;
            t = p1[ro + cc2]; a2 = v2 ? t : 0.f;
            t = p2[ro + cc2]; b2 = v2 ? t : 0.f;
        } else {
            a0 = b0 = a1 = b1 = a2 = b2 = 0.f;
        }
    };

    auto write_row = [&](int r) {
        float2* __restrict__ dst = sAB[wv][r & 1];
        dst[l]      = make_float2(a0, b0);
        dst[l + 64] = make_float2(a1, b1);
        if (l < 10) dst[l + 128] = make_float2(a2, b2);
    };

    // accumulator ring: slot s holds output row o with o%11==s (.x=col0,.y=col1)
    float2 acc0[11], acc1[11], acc2[11], acc3[11], acc4[11];
    #pragma unroll
    for (int s = 0; s < 11; ++s)
        acc0[s] = acc1[s] = acc2[s] = acc3[s] = acc4[s] = make_float2(0.f, 0.f);

    float tsum = 0.f;

    // prologue: row 0 into LDS, row 1 into prefetch regs
    load_row(0);
    write_row(0);
    load_row(1);

    #pragma unroll 1
    for (int g = 0; g < 7; ++g) {
        #pragma unroll
        for (int j = 0; j < 11; ++j) {
            const int r = g * 11 + j;    // staged row being consumed, 0..76

            write_row(r + 1);            // row r+1 from prefetch regs
            load_row(r + 2);             // issue next loads (consumed next iter)

            const int p = (g + j) & 1;   // parity of r

            // ---- 12-pair window: 6 x ds_read_b128 (byte offset 16*l) ----
            const float4* __restrict__ q4 =
                reinterpret_cast<const float4*>(&sAB[wv][p][2 * l]);
            const float4 t0 = q4[0], t1 = q4[1], t2 = q4[2];
            const float4 t3 = q4[3], t4 = q4[4], t5 = q4[5];
            const float2 P[12] = {
                {t0.x, t0.y}, {t0.z, t0.w}, {t1.x, t1.y}, {t1.z, t1.w},
                {t2.x, t2.y}, {t2.z, t2.w}, {t3.x, t3.y}, {t3.z, t3.w},
                {t4.x, t4.y}, {t4.z, t4.w}, {t5.x, t5.y}, {t5.z, t5.w}};

            // ---- horizontal 11-tap conv, 2 columns ----
            float2 hx = {0.f, 0.f}, hy = {0.f, 0.f}, hxx = {0.f, 0.f},
                   hyy = {0.f, 0.f}, hxy = {0.f, 0.f};
            #pragma unroll
            for (int k = 0; k < 11; ++k) {
                const float wk = wt.w[k];
                {   // column 0 (strip col 2l) uses pairs k
                    const float a = P[k].x, b = P[k].y;
                    const float ta = wk * a, tb = wk * b;
                    hx.x += ta; hy.x += tb;
                    hxx.x += ta * a; hyy.x += tb * b; hxy.x += ta * b;
                }
                {   // column 1 (strip col 2l+1) uses pairs k+1
                    const float a = P[k + 1].x, b = P[k + 1].y;
                    const float ta = wk * a, tb = wk * b;
                    hx.y += ta; hy.y += tb;
                    hxx.y += ta * a; hyy.y += tb * b; hxy.y += ta * b;
                }
            }

            // ---- vertical conv: scatter into ring; wi==0 assigns ----
            #pragma unroll
            for (int s = 0; s < 11; ++s) {
                const int wi = (j - s + 11) % 11;   // compile-time
                const float wk = wt.w[wi];
                if (wi == 0) {
                    acc0[s].x = wk * hx.x;  acc0[s].y = wk * hx.y;
                    acc1[s].x = wk * hy.x;  acc1[s].y = wk * hy.y;
                    acc2[s].x = wk * hxx.x; acc2[s].y = wk * hxx.y;
                    acc3[s].x = wk * hyy.x; acc3[s].y = wk * hyy.y;
                    acc4[s].x = wk * hxy.x; acc4[s].y = wk * hxy.y;
                } else {
                    acc0[s].x += wk * hx.x;  acc0[s].y += wk * hx.y;
                    acc1[s].x += wk * hy.x;  acc1[s].y += wk * hy.y;
                    acc2[s].x += wk * hxx.x; acc2[s].y += wk * hxx.y;
                    acc3[s].x += wk * hyy.x; acc3[s].y += wk * hyy.y;
                    acc4[s].x += wk * hxy.x; acc4[s].y += wk * hxy.y;
                }
            }

            // ---- emit output row o = r-10 (slot (j+1)%11) ----
            const int se = (j + 1) % 11;            // compile-time
            const int o = r - 10;
            const bool valid = (o >= 0) && (o < TH);
            const float sv =
                ssim_px(acc0[se].x, acc1[se].x, acc2[se].x, acc3[se].x,
                        acc4[se].x) +
                ssim_px(acc0[se].y, acc1[se].y, acc2[se].y, acc3[se].y,
                        acc4[se].y);
            tsum += valid ? sv : 0.f;
        }
    }

    // ---- block reduction (the only barrier in the kernel) ----
    #pragma unroll
    for (int off = 32; off > 0; off >>= 1)
        tsum += __shfl_down(tsum, off);
    if (l == 0) wave_sums[wv] = tsum;
    __syncthreads();
    if (tid == 0) {
        partial[blockIdx.x] =
            wave_sums[0] + wave_sums[1] + wave_sums[2] + wave_sums[3];
    }
}

__global__ __launch_bounds__(256) void reduce_kernel(
    const float* __restrict__ partial, int n, float* __restrict__ out,
    double inv_count)
{
    __shared__ double wave_sums[4];
    const int tid = threadIdx.x;
    double s = 0.0;
    for (int i = tid; i < n; i += 256) s += (double)partial[i];
    #pragma unroll
    for (int off = 32; off > 0; off >>= 1)
        s += __shfl_down(s, off);
    if ((tid & 63) == 0) wave_sums[tid >> 6] = s;
    __syncthreads();
    if (tid == 0) {
        out[0] = (float)((wave_sums[0] + wave_sums[1] +
                          wave_sums[2] + wave_sums[3]) * inv_count);
    }
}

extern "C" void kernel_launch(void* const* d_in, const int* in_sizes, int n_in,
                              void* d_out, int out_size, void* d_ws, size_t ws_size,
                              hipStream_t stream)
{
    const float* img1 = (const float*)d_in[0];
    const float* img2 = (const float*)d_in[1];
    float* out = (float*)d_out;
    float* partial = (float*)d_ws;   // 768 floats = 3 KB scratch

    // Gaussian window (ws=11, sigma=1.5) in fp32, matching the reference
    Weights wt;
    {
        float s = 0.f;
        for (int i = 0; i < 11; ++i) {
            const float d = (float)(i - 5);
            wt.w[i] = expf(-(d * d) / 4.5f);
            s += wt.w[i];
        }
        for (int i = 0; i < 11; ++i) wt.w[i] /= s;
    }

    const int nblocks = NCH * 8;     // 768

    ssim_kernel<<<nblocks, 256, 0, stream>>>(img1, img2, partial, wt);

    const double inv_count = 1.0 / ((double)NCH * IH * IW);
    reduce_kernel<<<1, 256, 0, stream>>>(partial, nblocks, out, inv_count);
}